// Round 6
// baseline (330.788 us; speedup 1.0000x reference)
//
#include <hip/hip_runtime.h>
#include <math.h>

#define N_NODES 50000
#define N_EDGES 1600000
#define IN_DIM 128
#define N_HEADS 8
#define OUT_DIM 16
#define HD 128            // N_HEADS * OUT_DIM
#define NBUCK 784         // dst>>6: 64 nodes per bucket
#define BCAP 2560         // region capacity per bucket (avg ~2041)
#define CHUNK 4096        // edges per bin block
#define BIN_BLOCKS ((N_EDGES + CHUNK - 1) / CHUNK)   // 391
#define NTILE 3125        // 50000/16 M-tiles (exact)
#define PBLK ((NTILE + 3) / 4)                        // 782 proj blocks (4 waves each)
#define TROW 132          // LDS tile row stride in floats (128 + 4 pad)
#define LOG2E 1.4426950408889634f
#define NPH 7             // src phases: phase = src >> 13 (8192 nodes = 2 MB ftb slice)
#define NB2 (NPH * NBUCK) // 5488 (phase, dst-bucket) cells
#define AGG_BLOCKS 1024   // 4 blocks/CU, co-resident persistent
#define AGG_WAVES (AGG_BLOCKS * 4)                    // 4096 persistent waves
#define NPW 13            // max nodes per wave (50000/4096 -> 12..13)

typedef __attribute__((ext_vector_type(8))) short bf16x8;
typedef __attribute__((ext_vector_type(4))) float f32x4;

__device__ __forceinline__ unsigned short f2bf(float f) {
    union { float f; unsigned int u; } v; v.f = f;
    unsigned int u = v.u;
    unsigned int r = (u + 0x7fffu + ((u >> 16) & 1u)) >> 16;   // RN-even
    return (unsigned short)r;
}

// exclusive scan of arr[0..NBUCK) in place; part[256] scratch; all 256 threads.
__device__ __forceinline__ void scan_nbuck_excl(int* arr, int* part) {
    int t = threadIdx.x;
    int v0 = 0, v1 = 0, v2 = 0, v3 = 0, cs = 0;
    if (t < NBUCK / 4) {
        v0 = arr[4 * t]; v1 = arr[4 * t + 1]; v2 = arr[4 * t + 2]; v3 = arr[4 * t + 3];
        cs = v0 + v1 + v2 + v3;
    }
    part[t] = cs;
    __syncthreads();
    for (int d = 1; d < 256; d <<= 1) {
        int u = (t >= d) ? part[t - d] : 0;
        __syncthreads();
        part[t] += u;
        __syncthreads();
    }
    if (t < NBUCK / 4) {
        int run = part[t] - cs;
        arr[4 * t] = run; run += v0;
        arr[4 * t + 1] = run; run += v1;
        arr[4 * t + 2] = run; run += v2;
        arr[4 * t + 3] = run;
    }
    __syncthreads();
}

// exclusive scan over arr[0..n) in place (n <= 256*K any), part[256] scratch.
__device__ __forceinline__ void scan_flat_excl(int* arr, int n, int* part) {
    int t = threadIdx.x;
    int K = (n + 255) / 256;
    int base = t * K;
    int cs = 0;
    for (int k = 0; k < K; k++) { int idx = base + k; if (idx < n) cs += arr[idx]; }
    part[t] = cs;
    __syncthreads();
    for (int d = 1; d < 256; d <<= 1) {
        int u = (t >= d) ? part[t - d] : 0;
        __syncthreads();
        part[t] += u;
        __syncthreads();
    }
    int run = part[t] - cs;
    for (int k = 0; k < K; k++) {
        int idx = base + k;
        if (idx < n) { int v = arr[idx]; arr[idx] = run; run += v; }
    }
    __syncthreads();
}

// ---------------- prep: W(f32) -> Wb(bf16) + zero counters + sentinel rows ----
// Sentinel node N_NODES: a1 row = -inf (exp2 -> 0 => free edge masking in
// aggregate), ftb row = 0 (so e=0 times finite 0 => no NaN).
__global__ void k_prep(const float* __restrict__ W, unsigned short* __restrict__ Wb,
                       int* __restrict__ bucket_cnt, int* __restrict__ cntp,
                       int* __restrict__ ovf_cnt,
                       unsigned short* __restrict__ ftb, float* __restrict__ a1) {
    int g = blockIdx.x * 256 + threadIdx.x;   // 32 blocks -> 8192 threads
    if (g < NBUCK) bucket_cnt[g] = 0;
    if (g < NB2) cntp[g] = 0;
    if (g == 0) *ovf_cnt = 0;
    if (g < 64) ((unsigned int*)(ftb + (size_t)N_NODES * HD))[g] = 0u;
    if (g >= 64 && g < 64 + N_HEADS)
        a1[(size_t)N_NODES * N_HEADS + (g - 64)] = __int_as_float(0xff800000); // -inf
    if (g >= (HD * IN_DIM) / 4) return;
    float4 v = ((const float4*)W)[g];
    ushort4 us;
    us.x = f2bf(v.x); us.y = f2bf(v.y); us.z = f2bf(v.z); us.w = f2bf(v.w);
    ((ushort4*)Wb)[g] = us;
}

// ---------------- fused: MFMA projection (blocks < PBLK) | edge binning ----------
__global__ __launch_bounds__(256) void k_proj_bin(
    const float* __restrict__ x, const unsigned short* __restrict__ Wb,
    const float* __restrict__ attn_l, const float* __restrict__ attn_r,
    unsigned short* __restrict__ ftb, float* __restrict__ a1, float* __restrict__ a2,
    const int* __restrict__ src, const int* __restrict__ dst,
    unsigned int* __restrict__ region, int* __restrict__ bucket_cnt,
    int* __restrict__ cntp, int* __restrict__ ovf_cnt, unsigned int* __restrict__ ovf) {
    // union: proj 4 wave-private f32 tiles 16x132 (33792 B) | bin 23680 B
    __shared__ __align__(16) char smem[4 * 16 * TROW * 4];
    int tid = threadIdx.x;

    if (blockIdx.x < PBLK) {
        // ---------------- MFMA projection branch ----------------
        int wid  = tid >> 6;
        int tile = blockIdx.x * 4 + wid;
        if (tile >= NTILE) return;           // no barriers in this branch
        int lane = tid & 63;
        int m = lane & 15, q = lane >> 4;
        int node0 = tile * 16;

        // A fragments: x[node0+m][ks*32 + q*8 .. +7], fp32 -> bf16
        const float* xr = x + (size_t)(node0 + m) * IN_DIM + q * 8;
        float4 xa[4][2];
#pragma unroll
        for (int ks = 0; ks < 4; ks++) {
            xa[ks][0] = *(const float4*)(xr + ks * 32);
            xa[ks][1] = *(const float4*)(xr + ks * 32 + 4);
        }
        bf16x8 afr[4];
#pragma unroll
        for (int ks = 0; ks < 4; ks++) {
            afr[ks][0] = (short)f2bf(xa[ks][0].x); afr[ks][1] = (short)f2bf(xa[ks][0].y);
            afr[ks][2] = (short)f2bf(xa[ks][0].z); afr[ks][3] = (short)f2bf(xa[ks][0].w);
            afr[ks][4] = (short)f2bf(xa[ks][1].x); afr[ks][5] = (short)f2bf(xa[ks][1].y);
            afr[ks][6] = (short)f2bf(xa[ks][1].z); afr[ks][7] = (short)f2bf(xa[ks][1].w);
        }

        float* tl = (float*)smem + wid * (16 * TROW);

        // heads loop: B frag = Wb[h*16+m][ks*32 + q*8 .. +7] (original W layout!)
#pragma unroll
        for (int h = 0; h < N_HEADS; h++) {
            const unsigned short* wrow = Wb + (size_t)(h * 16 + m) * IN_DIM + q * 8;
            f32x4 c = {0.f, 0.f, 0.f, 0.f};
#pragma unroll
            for (int ks = 0; ks < 4; ks++) {
                bf16x8 bfr = *(const bf16x8*)(wrow + ks * 32);
                c = __builtin_amdgcn_mfma_f32_16x16x32_bf16(afr[ks], bfr, c, 0, 0, 0);
            }
            // C layout: col = lane&15, row = q*4 + reg  -> stash in LDS tile
#pragma unroll
            for (int r = 0; r < 4; r++)
                tl[(q * 4 + r) * TROW + h * 16 + m] = c[r];
        }

        // a1/a2: lane -> node (lane&15), heads {lane>>4, (lane>>4)+4}
        // NOTE: pre-scaled by log2(e) so aggregate can use raw v_exp_f32 (2^x).
        int nd = lane & 15;
#pragma unroll
        for (int hi = 0; hi < 2; hi++) {
            int hh = (lane >> 4) + hi * 4;
            const float4* rowv = (const float4*)(tl + nd * TROW + hh * 16);
            const float4* alv  = (const float4*)(attn_l + hh * OUT_DIM);
            const float4* arv  = (const float4*)(attn_r + hh * OUT_DIM);
            float sl = 0.f, sr = 0.f;
#pragma unroll
            for (int d4 = 0; d4 < 4; d4++) {
                float4 fv = rowv[d4];
                float4 al = alv[d4];
                float4 ar = arv[d4];
                sl += fv.x * al.x + fv.y * al.y + fv.z * al.z + fv.w * al.w;
                sr += fv.x * ar.x + fv.y * ar.y + fv.z * ar.z + fv.w * ar.w;
            }
            a1[(node0 + nd) * N_HEADS + hh] = sl * LOG2E;
            a2[(node0 + nd) * N_HEADS + hh] = sr * LOG2E;
        }

        // ft store: pass p covers rows p*4+q; lane m covers 8 cols
#pragma unroll
        for (int p = 0; p < 4; p++) {
            int r = p * 4 + q;
            const float* srcp = tl + r * TROW + m * 8;
            float4 f0 = *(const float4*)(srcp);
            float4 f1 = *(const float4*)(srcp + 4);
            ushort4 u0, u1;
            u0.x = f2bf(f0.x); u0.y = f2bf(f0.y); u0.z = f2bf(f0.z); u0.w = f2bf(f0.w);
            u1.x = f2bf(f1.x); u1.y = f2bf(f1.y); u1.z = f2bf(f1.z); u1.w = f2bf(f1.w);
            ushort4* dstp = (ushort4*)(ftb + (size_t)(node0 + r) * HD + m * 8);
            dstp[0] = u0;
            dstp[1] = u1;
        }
    } else {
        // ---------------- binning branch ----------------
        unsigned int* stage = (unsigned int*)smem;          // 16 KB
        int* hist  = (int*)(smem + 16384);                  // NBUCK
        int* delta = (int*)(smem + 19520);                  // NBUCK
        int* part  = (int*)(smem + 22656);                  // 256

        int t = tid;
        int base = (blockIdx.x - PBLK) * CHUNK;
        int nvalid = min(CHUNK, N_EDGES - base);

        for (int i = t; i < NBUCK; i += 256) hist[i] = 0;
        __syncthreads();

        unsigned int mypack[CHUNK / 256];
#pragma unroll
        for (int k = 0; k < CHUNK / 256; k++) {
            int i = t + k * 256;
            if (i < nvalid) {
                int s = src[base + i];
                int d = dst[base + i];
                unsigned int p = ((unsigned int)d << 16) | (unsigned int)s;
                mypack[k] = p;
                atomicAdd(&hist[d >> 6], 1);
                atomicAdd(&cntp[(s >> 13) * NBUCK + (d >> 6)], 1);  // (phase,bucket) totals
            }
        }
        __syncthreads();
        for (int i = t; i < NBUCK; i += 256) {
            int h = hist[i];
            delta[i] = (h > 0) ? atomicAdd(&bucket_cnt[i], h) : 0;
        }
        __syncthreads();
        scan_nbuck_excl(hist, part);            // hist -> local exclusive offsets
        for (int i = t; i < NBUCK; i += 256) delta[i] -= hist[i];
        __syncthreads();
#pragma unroll
        for (int k = 0; k < CHUNK / 256; k++) {
            int i = t + k * 256;
            if (i < nvalid) {
                unsigned int p = mypack[k];
                int slot = atomicAdd(&hist[p >> 22], 1);
                stage[slot] = p;
            }
        }
        __syncthreads();
        for (int i = t; i < nvalid; i += 256) {
            unsigned int p = stage[i];
            int b = p >> 22;
            int pos = delta[b] + i;
            if (pos < BCAP) region[(size_t)b * BCAP + pos] = p;
            else { int o = atomicAdd(ovf_cnt, 1); ovf[o] = p; }
        }
    }
}

// ---------------- k_place v7: GLOBAL phase-major placement ----------------------
// esrc is sorted by (phase, dst): within phase p, node n's segment is contiguous
// and node order is global (bucket-major matches node-major). Emits the CSR
// nps2[p*(N+1)+n] = start of node n's phase-p segment; nps2[p][N] = phase end.
// Per-bucket output goes to 7 discontiguous global ranges; stage locally in LDS
// (phase-major local layout) then 7 coalesced copy-outs.
__global__ __launch_bounds__(256) void k_place(
    const unsigned int* __restrict__ region, const int* __restrict__ bucket_cnt,
    const int* __restrict__ cntp, const int* __restrict__ ovf_cnt,
    const unsigned int* __restrict__ ovf,
    int* __restrict__ nps2, unsigned short* __restrict__ esrc) {
    int b = blockIdx.x;
    int t = threadIdx.x;
    __shared__ int cpb[NB2], part[256];
    __shared__ int hist[NPH * 64];      // (phase-major, node-minor) counts -> offsets
    __shared__ int curs[NPH * 64];
    __shared__ int gstart[NPH], lstart[NPH], phtot[NPH];
    __shared__ unsigned short sstage[BCAP];

    for (int i = t; i < NB2; i += 256) cpb[i] = cntp[i];
    for (int i = t; i < NPH * 64; i += 256) hist[i] = 0;
    __syncthreads();
    scan_flat_excl(cpb, NB2, part);     // global phase-major exclusive positions

    int truec = bucket_cnt[b];
    int rc = min(truec, BCAP);
    bool fits = (truec <= BCAP);        // statistically always true
    const unsigned int* reg = region + (size_t)b * BCAP;

    for (int i = t; i < rc; i += 256) {
        unsigned int pk = reg[i];
        int key = (int)((pk & 0xffffu) >> 13) * 64 + (int)((pk >> 16) & 63);
        atomicAdd(&hist[key], 1);
    }
    int no = 0;
    if (truec > BCAP) {                 // correctness fallback
        no = *ovf_cnt;
        for (int i = t; i < no; i += 256)
            if ((int)(ovf[i] >> 22) == b) {
                unsigned int pk = ovf[i];
                int key = (int)((pk & 0xffffu) >> 13) * 64 + (int)((pk >> 16) & 63);
                atomicAdd(&hist[key], 1);
            }
    }
    __syncthreads();
    scan_flat_excl(hist, NPH * 64, part);   // local phase-major layout offsets

    if (t < NPH) {
        gstart[t] = cpb[t * NBUCK + b];
        lstart[t] = hist[t * 64];
        phtot[t]  = ((t == NPH - 1) ? truec : hist[(t + 1) * 64]) - hist[t * 64];
    }
    __syncthreads();

    for (int i = t; i < NPH * 64; i += 256) {
        int p = i >> 6, nl = i & 63;
        int node = b * 64 + nl;
        if (node < N_NODES)
            nps2[(size_t)p * (N_NODES + 1) + node] = gstart[p] + (hist[i] - lstart[p]);
        curs[i] = fits ? hist[i] : (gstart[p] + hist[i] - lstart[p]);
    }
    if (b == 0 && t < NPH)
        nps2[(size_t)t * (N_NODES + 1) + N_NODES] =
            (t == NPH - 1) ? N_EDGES : cpb[(t + 1) * NBUCK];
    __syncthreads();

    for (int i = t; i < rc; i += 256) {
        unsigned int pk = reg[i];
        int key = (int)((pk & 0xffffu) >> 13) * 64 + (int)((pk >> 16) & 63);
        int pos = atomicAdd(&curs[key], 1);
        if (fits) sstage[pos] = (unsigned short)(pk & 0xffffu);
        else      esrc[pos]  = (unsigned short)(pk & 0xffffu);
    }
    if (truec > BCAP) {
        for (int i = t; i < no; i += 256) {
            unsigned int pk = ovf[i];
            if ((int)(pk >> 22) == b) {
                int key = (int)((pk & 0xffffu) >> 13) * 64 + (int)((pk >> 16) & 63);
                int pos = atomicAdd(&curs[key], 1);
                esrc[pos] = (unsigned short)(pk & 0xffffu);
            }
        }
    }
    __syncthreads();
    if (fits) {
        for (int p = 0; p < NPH; p++)
            for (int i = t; i < phtot[p]; i += 256)
                esrc[gstart[p] + i] = sstage[lstart[p] + i];   // coalesced copy-out
    }
}

// ---------------- aggregation v7: phase-major contiguous stream -----------------
// Wave owns CONTIGUOUS nodes [n0,n1); per phase its edges are one contiguous
// esrc range (v6's 91 serial mini-segments -> 7 streams). R2's 2-buffered
// 8-slot gather pipeline restored; node boundaries are scalar bookkeeping
// (14 boundary SGPRs): per-slot pos>=B[curi+1] advances a temp-accumulator
// flush into acc[curi] via compile-time-unrolled uniform switch (SALU pipe).
// cura2 updated statically inside the switch (no dynamic reg indexing).
// Sentinel (a1[N]=-inf, ftb[N]=0) masks chunk-tail slots.
template <int KK>
__device__ __forceinline__ void issue8(int sv, const float* __restrict__ a1,
                                       const unsigned short* __restrict__ ftb,
                                       int hl, int dimoff,
                                       float* a1v, unsigned int* pv) {
#pragma unroll
    for (int j = 0; j < 8; j++) {
        int s = __builtin_amdgcn_readlane(sv, KK + j);   // SGPR -> scalar addressing
        a1v[j] = a1[(size_t)s * N_HEADS + hl];
        pv[j]  = *(const unsigned int*)(ftb + (size_t)s * HD + dimoff);
    }
}

#define FLUSH_ADV()                                                         \
    {                                                                       \
        _Pragma("unroll")                                                   \
        for (int q = 0; q < NPW; q++)                                       \
            if (q == curi) {                                                \
                accx[q] += tx; accy[q] += ty; lsum[q] += tl;                \
                cura2 = (q + 1 < NPW) ? a2h[q + 1] : 0.f;                   \
            }                                                               \
        tx = ty = tl = 0.f;                                                 \
    }

#define CONSUME8(AV, PV, KK)                                                \
    {                                                                       \
        _Pragma("unroll")                                                   \
        for (int j = 0; j < 8; j++) {                                       \
            int pos = cb + (KK) + j;                                        \
            while (curi < cnt - 1 && pos >= nb_end) {                       \
                FLUSH_ADV();                                                \
                curi++;                                                     \
                nb_end = __builtin_amdgcn_readlane(bnd, curi + 1);          \
            }                                                               \
            float tt = AV[j] + cura2;                                       \
            float uu = fmaxf(tt, 0.2f * tt);                                \
            float ee;                                                       \
            asm("v_exp_f32 %0, %1" : "=v"(ee) : "v"(uu));                   \
            tl += ee;                                                       \
            tx = fmaf(ee, __uint_as_float(PV[j] << 16), tx);                \
            ty = fmaf(ee, __uint_as_float(PV[j] & 0xffff0000u), ty);        \
        }                                                                   \
    }

__global__ __launch_bounds__(256, 4) void k_aggregate(
    const unsigned short* __restrict__ ftb, const float* __restrict__ a1,
    const float* __restrict__ a2, const int* __restrict__ nps2,
    const unsigned short* __restrict__ esrc, float* __restrict__ out) {
    int wid  = threadIdx.x >> 6;
    int lane = threadIdx.x & 63;
    int gw = blockIdx.x * 4 + wid;            // persistent wave id
    int hl = lane >> 3;                       // head for this lane's dim pair
    int dimoff = lane * 2;

    int n0 = __builtin_amdgcn_readfirstlane((int)(((long long)gw * N_NODES) / AGG_WAVES));
    int n1 = __builtin_amdgcn_readfirstlane((int)(((long long)(gw + 1) * N_NODES) / AGG_WAVES));
    int cnt = n1 - n0;                        // 12 or 13

    float accx[NPW], accy[NPW], lsum[NPW], a2h[NPW];
#pragma unroll
    for (int i = 0; i < NPW; i++) {
        accx[i] = 0.f; accy[i] = 0.f; lsum[i] = 0.f;
        int node = n0 + i; if (node > N_NODES - 1) node = N_NODES - 1;
        a2h[i] = a2[(size_t)node * N_HEADS + hl];
    }

    for (int p = 0; p < NPH; p++) {
        const int* P = nps2 + (size_t)p * (N_NODES + 1) + n0;
        int bidx = lane < cnt ? lane : cnt;
        int bnd = P[bidx];                                    // boundaries in lanes 0..cnt
        int pbeg = __builtin_amdgcn_readlane(bnd, 0);
        int pend = __builtin_amdgcn_readlane(bnd, cnt);

        int curi = 0;
        int nb_end = __builtin_amdgcn_readlane(bnd, 1);
        float tx = 0.f, ty = 0.f, tl = 0.f;
        float cura2 = a2h[0];

        for (int cb = pbeg; cb < pend; cb += 64) {
            int nbc = pend - cb; if (nbc > 64) nbc = 64;
            int v = (int)esrc[cb + lane];          // coalesced; global pad covers tail
            int sv = (lane < nbc) ? v : N_NODES;   // sentinel for tail slots

            float a1A[8], a1B[8];
            unsigned int pA[8], pB[8];
            issue8<0>(sv, a1, ftb, hl, dimoff, a1A, pA);
            if (nbc > 8)  issue8<8>(sv, a1, ftb, hl, dimoff, a1B, pB);
            CONSUME8(a1A, pA, 0);
            if (nbc > 16) issue8<16>(sv, a1, ftb, hl, dimoff, a1A, pA);
            if (nbc > 8)  CONSUME8(a1B, pB, 8);
            if (nbc > 24) issue8<24>(sv, a1, ftb, hl, dimoff, a1B, pB);
            if (nbc > 16) CONSUME8(a1A, pA, 16);
            if (nbc > 32) issue8<32>(sv, a1, ftb, hl, dimoff, a1A, pA);
            if (nbc > 24) CONSUME8(a1B, pB, 24);
            if (nbc > 40) issue8<40>(sv, a1, ftb, hl, dimoff, a1B, pB);
            if (nbc > 32) CONSUME8(a1A, pA, 32);
            if (nbc > 48) issue8<48>(sv, a1, ftb, hl, dimoff, a1A, pA);
            if (nbc > 40) CONSUME8(a1B, pB, 40);
            if (nbc > 56) issue8<56>(sv, a1, ftb, hl, dimoff, a1B, pB);
            if (nbc > 48) CONSUME8(a1A, pA, 48);
            if (nbc > 56) CONSUME8(a1B, pB, 56);
        }
        // drain: flush remaining temps through the node list
        for (;;) {
            FLUSH_ADV();
            if (curi >= cnt - 1) break;
            curi++;
        }
    }

#pragma unroll
    for (int i = 0; i < NPW; i++) {
        if (i < cnt) {
            float invl = (lsum[i] > 0.f) ? 1.f / lsum[i] : 0.f;
            float2 o; o.x = accx[i] * invl; o.y = accy[i] * invl;
            *(float2*)(out + (size_t)(n0 + i) * HD + dimoff) = o;
        }
    }
}

// ---------------- host launcher ----------------
extern "C" void kernel_launch(void* const* d_in, const int* in_sizes, int n_in,
                              void* d_out, int out_size, void* d_ws, size_t ws_size,
                              hipStream_t stream) {
    const float* x      = (const float*)d_in[0];
    const float* W      = (const float*)d_in[1];
    const float* attn_l = (const float*)d_in[2];
    const float* attn_r = (const float*)d_in[3];
    const int*   src    = (const int*)d_in[4];
    const int*   dst    = (const int*)d_in[5];
    float* out = (float*)d_out;

    char* ws = (char*)d_ws;
    size_t o = 0;
    auto alloc = [&](size_t bytes) -> char* {
        char* p = ws + o;
        o = (o + bytes + 255) & ~(size_t)255;
        return p;
    };
    // +1 sentinel row on ftb (zeros) and a1 (-inf)
    unsigned short* ftb  = (unsigned short*)alloc((size_t)(N_NODES + 1) * HD * 2);
    float* a1            = (float*)alloc((size_t)(N_NODES + 1) * N_HEADS * 4);
    float* a2            = (float*)alloc((size_t)N_NODES * N_HEADS * 4);
    unsigned short* Wb   = (unsigned short*)alloc((size_t)HD * IN_DIM * 2);    // 32 KB
    unsigned int* region = (unsigned int*)alloc((size_t)NBUCK * BCAP * 4);     // 8.0 MB
    int* bucket_cnt      = (int*)alloc((size_t)NBUCK * 4);
    int* cntp            = (int*)alloc((size_t)NB2 * 4);                       // 22 KB
    int* ovf_cnt         = (int*)alloc(4);
    unsigned int* ovf    = (unsigned int*)alloc((size_t)N_EDGES * 4);          // 6.4 MB
    int* nps2            = (int*)alloc((size_t)NPH * (N_NODES + 1) * 4);       // 1.4 MB
    unsigned short* esrc = (unsigned short*)alloc((size_t)N_EDGES * 2 + 256);  // +pad for over-read

    (void)in_sizes; (void)n_in; (void)out_size; (void)ws_size;

    k_prep<<<32, 256, 0, stream>>>(W, Wb, bucket_cnt, cntp, ovf_cnt, ftb, a1);
    k_proj_bin<<<PBLK + BIN_BLOCKS, 256, 0, stream>>>(
        x, Wb, attn_l, attn_r, ftb, a1, a2,
        src, dst, region, bucket_cnt, cntp, ovf_cnt, ovf);
    k_place<<<NBUCK, 256, 0, stream>>>(region, bucket_cnt, cntp, ovf_cnt, ovf, nps2, esrc);
    k_aggregate<<<AGG_BLOCKS, 256, 0, stream>>>(ftb, a1, a2, nps2, esrc, out);
}